// Round 7
// baseline (695.749 us; speedup 1.0000x reference)
//
#include <hip/hip_runtime.h>

typedef __bf16 bf16;
typedef __bf16 bf16x4 __attribute__((ext_vector_type(4)));
typedef __bf16 bf16x8 __attribute__((ext_vector_type(8)));
typedef float f32x4 __attribute__((ext_vector_type(4)));

#define BM 128
#define BN 128
#define BK 32

// ---------------- async global->LDS (16B per lane) ----------------
__device__ __forceinline__ void async16(const void* g, void* l) {
    __builtin_amdgcn_global_load_lds(
        (__attribute__((address_space(1))) void*)g,
        (__attribute__((address_space(3))) void*)l,
        16, 0, 0);
}

// =============================================================================
// Proj GEMM: m97 structure (128^2, 16 KiB LDS, 256 thr, ~3 blocks/CU).
// R4-R6 lesson: 256^2 1-block/CU lockstep schedules all stall at 25-27%
// MfmaUtil (stage+vmcnt+barrier critical path). m97's 37% comes from
// 12 waves/CU implicit overlap (m114), not explicit pipelining.
// Grid: 1-D, m-fastest (24 M-tiles share a W panel) + bijective XCD swizzle.
// Epilogue: LDS-transpose (4 x 32-row passes through the 16 KiB buffer,
// 2-way-max bank swizzle) -> contiguous cached f32x4 stores (R4 win:
// WRITE_SIZE == ideal 640 MB).
// =============================================================================
__global__ __launch_bounds__(256) void gemm128(
    const bf16* __restrict__ A, const bf16* __restrict__ W,
    float* __restrict__ C, int K, int ldo, int Nstore, int nTilesM)
{
    __shared__ __align__(16) unsigned char smem[16384];
    bf16* As = (bf16*)smem;            // [128][32]
    bf16* Ws = (bf16*)(smem + 8192);   // [128][32]

    int nwg = gridDim.x;
    int orig = blockIdx.x;
    int q = nwg >> 3, r = nwg & 7, xcd = orig & 7, local = orig >> 3;
    int wgid = (xcd < r ? xcd * (q + 1) : r * (q + 1) + (xcd - r) * q) + local;
    const int brow = (wgid % nTilesM) * BM;
    const int bcol = (wgid / nTilesM) * BN;

    const int t = threadIdx.x;
    const int wv = t >> 6;
    const int lane = t & 63;
    const int wrow = (wv >> 1) * 64;
    const int wcol = (wv & 1) * 64;

    f32x4 acc[4][4] = {};

    const int row0 = t >> 2;
    const int cg = (t & 3) * 8;
    const bf16* gA = A + (size_t)(brow + row0) * K + cg;
    const bf16* gW = W + (size_t)(bcol + row0) * K + cg;
    const size_t rstep = (size_t)64 * K;
    bf16* lA0 = As + wv * 512;
    bf16* lA1 = As + 2048 + wv * 512;
    bf16* lW0 = Ws + wv * 512;
    bf16* lW1 = Ws + 2048 + wv * 512;

    const int lrow = lane & 15;
    const int kg = (lane >> 4) * 8;

    for (int k0 = 0; k0 < K; k0 += BK) {
        if (k0) __syncthreads();
        async16(gA + k0, lA0);
        async16(gA + rstep + k0, lA1);
        async16(gW + k0, lW0);
        async16(gW + rstep + k0, lW1);
        __syncthreads();
        bf16x8 af[4], wf[4];
        #pragma unroll
        for (int i = 0; i < 4; i++)
            af[i] = *(const bf16x8*)(As + (wrow + i * 16 + lrow) * BK + kg);
        #pragma unroll
        for (int j = 0; j < 4; j++)
            wf[j] = *(const bf16x8*)(Ws + (wcol + j * 16 + lrow) * BK + kg);
        #pragma unroll
        for (int i = 0; i < 4; i++)
            #pragma unroll
            for (int j = 0; j < 4; j++)
                acc[i][j] = __builtin_amdgcn_mfma_f32_16x16x32_bf16(
                    af[i], wf[j], acc[i][j], 0, 0, 0);
    }

    // ---- epilogue: 4 passes of 32 rows x 128 f32 (16 KiB) through LDS ------
    // write swizzle: col ^ ((lrow&4)<<2)  (flip bank half across rb groups)
    float* ldsf = (float*)smem;
    const int lcol = lane & 15;
    const int rb = (lane >> 4) * 4;
    #pragma unroll
    for (int p = 0; p < 4; p++) {
        __syncthreads();   // prior LDS reads (main loop / prev pass) complete
        if ((wv >> 1) == (p >> 1)) {
            #pragma unroll
            for (int di = 0; di < 2; di++) {
                const int i = 2 * (p & 1) + di;
                #pragma unroll
                for (int j = 0; j < 4; j++) {
                    #pragma unroll
                    for (int r2 = 0; r2 < 4; r2++) {
                        int lr2 = di * 16 + rb + r2;
                        int col = wcol + j * 16 + lcol;
                        ldsf[lr2 * 128 + (col ^ ((lr2 & 4) << 2))] = acc[i][j][r2];
                    }
                }
            }
        }
        __syncthreads();
        #pragma unroll
        for (int it = 0; it < 4; it++) {
            int c = it * 256 + t;              // 0..1023 chunks of 16B
            int lr2 = c >> 5, ch = c & 31;
            f32x4 v = *(const f32x4*)(ldsf + lr2 * 128 + (ch ^ (lr2 & 4)) * 4);
            int grow = brow + p * 32 + lr2;
            int gcol = bcol + ch * 4;
            float* dst = C + (size_t)grow * ldo + gcol;
            if (gcol + 4 <= Nstore) {
                *(f32x4*)dst = v;
            } else {
                #pragma unroll
                for (int k2 = 0; k2 < 4; k2++)
                    if (gcol + k2 < Nstore) dst[k2] = v[k2];
            }
        }
    }
}

// ---------------- bf16 MFMA GEMM (128^2, m97 structure) for small GEMMs -----
__global__ __launch_bounds__(256) void gemm_bt(
    const bf16* __restrict__ A, const bf16* __restrict__ W,
    const float* __restrict__ bias,
    float* __restrict__ outF, bf16* __restrict__ outB,
    int M, int K, int ldo, int Nstore, int relu)
{
    __shared__ bf16 As[BM * BK];
    __shared__ bf16 Ws[BN * BK];
    const int brow = blockIdx.y * BM;
    const int bcol = blockIdx.x * BN;
    const int t = threadIdx.x;
    const int wv = t >> 6;
    const int lane = t & 63;
    const int wrow = (wv >> 1) * 64;
    const int wcol = (wv & 1) * 64;

    f32x4 acc[4][4] = {};

    const int row0 = t >> 2;
    const int cg = (t & 3) * 8;
    const bf16* gA = A + (size_t)(brow + row0) * K + cg;
    const bf16* gW = W + (size_t)(bcol + row0) * K + cg;
    const size_t rstep = (size_t)64 * K;
    bf16* lA0 = As + wv * 512;
    bf16* lA1 = As + 2048 + wv * 512;
    bf16* lW0 = Ws + wv * 512;
    bf16* lW1 = Ws + 2048 + wv * 512;

    const int lrow = lane & 15;
    const int kg = (lane >> 4) * 8;

    for (int k0 = 0; k0 < K; k0 += BK) {
        if (k0) __syncthreads();
        async16(gA + k0, lA0);
        async16(gA + rstep + k0, lA1);
        async16(gW + k0, lW0);
        async16(gW + rstep + k0, lW1);
        __syncthreads();
        bf16x8 af[4], wf[4];
        #pragma unroll
        for (int i = 0; i < 4; i++)
            af[i] = *(const bf16x8*)(As + (wrow + i * 16 + lrow) * BK + kg);
        #pragma unroll
        for (int j = 0; j < 4; j++)
            wf[j] = *(const bf16x8*)(Ws + (wcol + j * 16 + lrow) * BK + kg);
        #pragma unroll
        for (int i = 0; i < 4; i++)
            #pragma unroll
            for (int j = 0; j < 4; j++)
                acc[i][j] = __builtin_amdgcn_mfma_f32_16x16x32_bf16(
                    af[i], wf[j], acc[i][j], 0, 0, 0);
    }

    const int lcol = lane & 15;
    const int rb = (lane >> 4) * 4;
    #pragma unroll
    for (int j = 0; j < 4; j++) {
        int n = bcol + wcol + j * 16 + lcol;
        if (n >= Nstore) continue;
        float bv = bias ? bias[n] : 0.f;
        #pragma unroll
        for (int i = 0; i < 4; i++) {
            #pragma unroll
            for (int r = 0; r < 4; r++) {
                int m = brow + wrow + i * 16 + rb + r;
                float v = acc[i][j][r] + bv;
                if (relu) v = fmaxf(v, 0.f);
                size_t off = (size_t)m * ldo + n;
                if (outF) outF[off] = v;
                if (outB) outB[off] = (bf16)v;
            }
        }
    }
}

// ---------------- fp32 -> bf16 convert (zero-pads rows beyond nvalid) --------
// Non-temporal source reads: big weights (proj_w = 159MB) are read ONCE.
__global__ __launch_bounds__(256) void cvt_bf16(
    const float* __restrict__ in, bf16* __restrict__ out,
    size_t nvalid, size_t ntotal)
{
    size_t i = ((size_t)blockIdx.x * 256 + threadIdx.x) * 4;
    if (i >= ntotal) return;
    bf16x4 r;
    if (i < nvalid) {
        f32x4 f = __builtin_nontemporal_load((const f32x4*)(in + i));
        r[0] = (bf16)f[0]; r[1] = (bf16)f[1]; r[2] = (bf16)f[2]; r[3] = (bf16)f[3];
    } else {
        r[0] = (bf16)0.f; r[1] = (bf16)0.f; r[2] = (bf16)0.f; r[3] = (bf16)0.f;
    }
    *(bf16x4*)(out + i) = r;
}

// ---------------- build tgt = [start, emb[tok0], emb[tok1]] per sequence -----
__global__ __launch_bounds__(256) void build_tgt(
    const float* __restrict__ start, const float* __restrict__ emb,
    const int* __restrict__ toks, float* __restrict__ outF, bf16* __restrict__ outB)
{
    int r = blockIdx.x;               // 0..3071, r = n*3 + p
    int n = r / 3, p = r % 3;
    const float* src = (p == 0) ? start : emb + (size_t)toks[n * 3 + (p - 1)] * 768;
    int t = threadIdx.x;
    #pragma unroll
    for (int j = 0; j < 3; j++) {
        int c = t + j * 256;
        float v = src[c];
        outF[(size_t)r * 768 + c] = v;
        outB[(size_t)r * 768 + c] = (bf16)v;
    }
}

// ---------------- 3-token causal self-attention, one wave per (n,head) -------
__global__ __launch_bounds__(64) void attn3(
    const float* __restrict__ qkv, bf16* __restrict__ o)
{
    int blk = blockIdx.x;             // n*4 + h
    int n = blk >> 2, h = blk & 3;
    int lane = threadIdx.x;
    const float* base = qkv + (size_t)n * 3 * 2304 + h * 192;
    float q[3][3], k[3][3], v[3][3];
    #pragma unroll
    for (int p = 0; p < 3; p++)
        #pragma unroll
        for (int j = 0; j < 3; j++) {
            int d = lane + j * 64;
            q[p][j] = base[p * 2304 + d];
            k[p][j] = base[p * 2304 + 768 + d];
            v[p][j] = base[p * 2304 + 1536 + d];
        }
    float s[3][3];
    #pragma unroll
    for (int p = 0; p < 3; p++)
        #pragma unroll
        for (int pk = 0; pk < 3; pk++) {
            if (pk > p) continue;
            float ps = q[p][0] * k[pk][0] + q[p][1] * k[pk][1] + q[p][2] * k[pk][2];
            #pragma unroll
            for (int off = 32; off; off >>= 1) ps += __shfl_xor(ps, off);
            s[p][pk] = ps * 0.072168783648703220563f;   // 1/sqrt(192)
        }
    float a[3][3] = {};
    a[0][0] = 1.f;
    {
        float m = fmaxf(s[1][0], s[1][1]);
        float e0 = expf(s[1][0] - m), e1 = expf(s[1][1] - m);
        float inv = 1.f / (e0 + e1);
        a[1][0] = e0 * inv; a[1][1] = e1 * inv;
    }
    {
        float m = fmaxf(fmaxf(s[2][0], s[2][1]), s[2][2]);
        float e0 = expf(s[2][0] - m), e1 = expf(s[2][1] - m), e2 = expf(s[2][2] - m);
        float inv = 1.f / (e0 + e1 + e2);
        a[2][0] = e0 * inv; a[2][1] = e1 * inv; a[2][2] = e2 * inv;
    }
    bf16* ob = o + (size_t)n * 3 * 768 + h * 192;
    #pragma unroll
    for (int p = 0; p < 3; p++)
        #pragma unroll
        for (int j = 0; j < 3; j++) {
            float val = a[p][0] * v[0][j];
            if (p >= 1) val += a[p][1] * v[1][j];
            if (p >= 2) val += a[p][2] * v[2][j];
            ob[p * 768 + lane + j * 64] = (bf16)val;
        }
}

// ---------------- x = LN(a + b) ; b optionally broadcast over 3 positions ----
__global__ __launch_bounds__(256) void add_ln(
    const float* __restrict__ a, const float* __restrict__ b,
    const float* __restrict__ g, const float* __restrict__ be,
    float* __restrict__ outF, bf16* __restrict__ outB, int bcast)
{
    int r = blockIdx.x;
    int t = threadIdx.x;
    const float* ar = a + (size_t)r * 768;
    const float* br = b + (size_t)(bcast ? (r / 3) : r) * 768;
    float x[3];
    float s = 0.f, sq = 0.f;
    #pragma unroll
    for (int j = 0; j < 3; j++) {
        int c = t + j * 256;
        x[j] = ar[c] + br[c];
        s += x[j]; sq += x[j] * x[j];
    }
    #pragma unroll
    for (int off = 32; off; off >>= 1) {
        s += __shfl_xor(s, off);
        sq += __shfl_xor(sq, off);
    }
    __shared__ float ls[4], lq[4];
    int wv = t >> 6;
    if ((t & 63) == 0) { ls[wv] = s; lq[wv] = sq; }
    __syncthreads();
    s = ls[0] + ls[1] + ls[2] + ls[3];
    sq = lq[0] + lq[1] + lq[2] + lq[3];
    float mean = s * (1.f / 768.f);
    float var = sq * (1.f / 768.f) - mean * mean;
    float inv = rsqrtf(var + 1e-5f);
    #pragma unroll
    for (int j = 0; j < 3; j++) {
        int c = t + j * 256;
        float y = (x[j] - mean) * inv * g[c] + be[c];
        if (outF) outF[(size_t)r * 768 + c] = y;
        if (outB) outB[(size_t)r * 768 + c] = (bf16)y;
    }
}

// =============================================================================
static inline void run_gemm(const bf16* A, const bf16* W, const float* bias,
                            float* outF, bf16* outB, int M, int Npad, int K,
                            int ldo, int Nstore, int relu, hipStream_t s)
{
    dim3 grid(Npad / BN, M / BM);
    gemm_bt<<<grid, 256, 0, s>>>(A, W, bias, outF, outB, M, K, ldo, Nstore, relu);
}

static inline void run_cvt(const float* in, bf16* out, size_t nvalid,
                           size_t ntotal, hipStream_t s)
{
    int blocks = (int)((ntotal / 4 + 255) / 256);
    cvt_bf16<<<blocks, 256, 0, s>>>(in, out, nvalid, ntotal);
}

extern "C" void kernel_launch(void* const* d_in, const int* in_sizes, int n_in,
                              void* d_out, int out_size, void* d_ws, size_t ws_size,
                              hipStream_t stream)
{
    const float* enc      = (const float*)d_in[0];   // (1024, 768)
    const int*   toks     = (const int*)d_in[1];     // (1024, 3)
    const float* start    = (const float*)d_in[2];   // (1, 768)
    const float* emb      = (const float*)d_in[3];   // (51865, 768)
    const float* sa_in_w  = (const float*)d_in[4];   // (2304, 768)
    const float* sa_in_b  = (const float*)d_in[5];
    const float* sa_out_w = (const float*)d_in[6];   // (768, 768)
    const float* sa_out_b = (const float*)d_in[7];
    const float* ca_in_w  = (const float*)d_in[8];   // (2304, 768); only Wv used
    const float* ca_in_b  = (const float*)d_in[9];
    const float* ca_out_w = (const float*)d_in[10];  // (768, 768)
    const float* ca_out_b = (const float*)d_in[11];
    const float* lin1_w   = (const float*)d_in[12];  // (2048, 768)
    const float* lin1_b   = (const float*)d_in[13];
    const float* lin2_w   = (const float*)d_in[14];  // (768, 2048)
    const float* lin2_b   = (const float*)d_in[15];
    const float* ln1_g    = (const float*)d_in[16];
    const float* ln1_bb   = (const float*)d_in[17];
    const float* ln2_g    = (const float*)d_in[18];
    const float* ln2_bb   = (const float*)d_in[19];
    const float* ln3_g    = (const float*)d_in[20];
    const float* ln3_bb   = (const float*)d_in[21];
    const float* proj_w   = (const float*)d_in[22];  // (51865, 768)
    float* out = (float*)d_out;

    const int NTOK = 3072;          // B*T*NT
    const int NM   = 1024;          // B*T
    const int H    = 768;
    const int V    = 51865;
    const int VPAD = 51968;         // 406*128
    const int DFF  = 2048;

    char* p = (char*)d_ws;
    auto alloc = [&](size_t bytes) {
        void* r = (void*)p;
        p += (bytes + 255) & ~(size_t)255;
        return r;
    };
    float* tgt_f = (float*)alloc((size_t)NTOK * H * 4);
    float* x1_f  = (float*)alloc((size_t)NTOK * H * 4);
    float* x2_f  = (float*)alloc((size_t)NTOK * H * 4);
    float* big_f = (float*)alloc((size_t)NTOK * 2304 * 4);  // qkv / gemm fp32 outs
    bf16*  actA  = (bf16*)alloc((size_t)NTOK * 2304 * 2);   // bf16 activations A
    bf16*  actB  = (bf16*)alloc((size_t)NTOK * DFF * 2);    // bf16 activations B
    bf16*  Wbf   = (bf16*)alloc((size_t)VPAD * H * 2);      // bf16 weights (reused)
    bf16*  mem_bf = actB;                                   // (1024,768) carved
    bf16*  v_bf   = actB + (size_t)NM * H;                  // (1024,768) carved
    float* cao_f  = big_f + (size_t)NTOK * H;               // (1024,768) carved

    // 1. tgt = [start, emb[t0], emb[t1]]
    build_tgt<<<NTOK, 256, 0, stream>>>(start, emb, toks, tgt_f, actA);

    // 2. qkv = tgt @ sa_in_w.T + b       (3072 x 2304)
    run_cvt(sa_in_w, Wbf, (size_t)2304 * H, (size_t)2304 * H, stream);
    run_gemm(actA, Wbf, sa_in_b, big_f, nullptr, NTOK, 2304, H, 2304, 2304, 0, stream);

    // 3. 3x3 causal attention -> o (bf16)
    attn3<<<NM * 4, 64, 0, stream>>>(big_f, actA);

    // 4. sa = o @ sa_out_w.T + b
    run_cvt(sa_out_w, Wbf, (size_t)H * H, (size_t)H * H, stream);
    run_gemm(actA, Wbf, sa_out_b, big_f, nullptr, NTOK, H, H, H, H, 0, stream);

    // 5. x1 = LN1(tgt + sa)
    add_ln<<<NTOK, 256, 0, stream>>>(tgt_f, big_f, ln1_g, ln1_bb, x1_f, nullptr, 0);

    // 6. cross-attn (Lk=1 => softmax==1 => output == V projection of memory)
    run_cvt(enc, mem_bf, (size_t)NM * H, (size_t)NM * H, stream);
    run_cvt(ca_in_w + (size_t)1536 * H, Wbf, (size_t)H * H, (size_t)H * H, stream);
    run_gemm(mem_bf, Wbf, ca_in_b + 1536, nullptr, v_bf, NM, H, H, H, H, 0, stream);
    run_cvt(ca_out_w, Wbf, (size_t)H * H, (size_t)H * H, stream);
    run_gemm(v_bf, Wbf, ca_out_b, cao_f, nullptr, NM, H, H, H, H, 0, stream);

    // 7. x2 = LN2(x1 + ca_out[broadcast])
    add_ln<<<NTOK, 256, 0, stream>>>(x1_f, cao_f, ln2_g, ln2_bb, x2_f, actA, 1);

    // 8. ff1 = relu(x2 @ lin1_w.T + b)   (bf16 only)
    run_cvt(lin1_w, Wbf, (size_t)DFF * H, (size_t)DFF * H, stream);
    run_gemm(actA, Wbf, lin1_b, nullptr, actB, NTOK, DFF, H, DFF, DFF, 1, stream);

    // 9. ff2 = ff1 @ lin2_w.T + b        (K = 2048)
    run_cvt(lin2_w, Wbf, (size_t)H * DFF, (size_t)H * DFF, stream);
    run_gemm(actB, Wbf, lin2_b, big_f, nullptr, NTOK, H, DFF, H, H, 0, stream);

    // 10. x3 = LN3(x2 + ff2) -> bf16 only
    add_ln<<<NTOK, 256, 0, stream>>>(x2_f, big_f, ln3_g, ln3_bb, nullptr, actA, 0);

    // 11. logits = x3 @ proj_w.T  (3072 x 51865) -- m97 128^2 kernel
    run_cvt(proj_w, Wbf, (size_t)V * H, (size_t)VPAD * H, stream);
    {
        const int nTilesM = NTOK / BM;            // 24
        dim3 grid(nTilesM * (VPAD / BN));          // 24 * 406 = 9744
        gemm128<<<grid, 256, 0, stream>>>(actA, Wbf, out, H, V, V, nTilesM);
    }
}

// Round 8
// 683.865 us; speedup vs baseline: 1.0174x; 1.0174x over previous
//
#include <hip/hip_runtime.h>

typedef __bf16 bf16;
typedef __bf16 bf16x4 __attribute__((ext_vector_type(4)));
typedef __bf16 bf16x8 __attribute__((ext_vector_type(8)));
typedef float f32x4 __attribute__((ext_vector_type(4)));

#define BM 128
#define BN 128
#define BK 32

// ---------------- async global->LDS (16B per lane) ----------------
__device__ __forceinline__ void async16(const void* g, void* l) {
    __builtin_amdgcn_global_load_lds(
        (__attribute__((address_space(1))) void*)g,
        (__attribute__((address_space(3))) void*)l,
        16, 0, 0);
}

// =============================================================================
// Proj GEMM: tile 128(M) x 256(N), BK=32, double-buffered (48 KiB LDS),
// 256 threads (4 waves), ~200 VGPR -> 2 waves/SIMD -> TWO independent
// blocks/CU. R4-R7 synthesis: 256-wide tile keeps FETCH low (203 panels,
// A stays L2/L3-resident, W fetched once); 2 blocks/CU gives cross-block
// MFMA<->VMEM overlap (m114) that the 1-block lockstep schedules lacked
// (all pinned at 25-27% MfmaUtil). One barrier per K-tile, 32 MFMA/wave
// per barrier. Epilogue: R4 LDS-transpose (8 x 16-row passes, XOR swizzle)
// -> contiguous cached f32x4 stores (WRITE == ideal 640 MB).
// =============================================================================
__global__ __launch_bounds__(256) void gemmWide(
    const bf16* __restrict__ A, const bf16* __restrict__ W,
    float* __restrict__ C, int K, int ldo, int Nstore, int nTilesM)
{
    __shared__ __align__(16) bf16 As[2][4096];   // 128x32 each -> 8 KiB x2
    __shared__ __align__(16) bf16 Ws[2][8192];   // 256x32 each -> 16 KiB x2

    // bijective XCD swizzle (m204) + m-fastest ordering for W-panel L2 reuse
    int nwg = gridDim.x;
    int orig = blockIdx.x;
    int q = nwg >> 3, r = nwg & 7, xcd = orig & 7, local = orig >> 3;
    int wgid = (xcd < r ? xcd * (q + 1) : r * (q + 1) + (xcd - r) * q) + local;
    const int brow = (wgid % nTilesM) * 128;
    const int bcol = (wgid / nTilesM) * 256;

    const int t = threadIdx.x;
    const int wv = t >> 6, lane = t & 63;
    const int wrow = (wv >> 1) * 64;      // 2x2 wave grid; per-wave out 64x128
    const int wcol = (wv & 1) * 128;
    const int lrow = lane & 15;
    const int kg = (lane >> 4) * 8;

    // staging source pointers: 64-row units, 4 chunks/row
    const int lr = t >> 2;                // 0..63
    const int c4 = (t & 3) * 8;
    const bf16* gA = A + (size_t)(brow + lr) * K + c4;
    const bf16* gW = W + (size_t)(bcol + lr) * K + c4;
    const size_t ks64 = (size_t)64 * K;
    const int dst = wv * 512;             // wave-uniform LDS base (HW adds lane*16B)

    f32x4 acc[4][8] = {};
    const int nkt = K >> 5;               // 24

    #define STAGE_W(buf, k0)                                   \
        async16(gA + (k0), &As[buf][0] + dst);                 \
        async16(gA + ks64 + (k0), &As[buf][2048] + dst);       \
        async16(gW + (k0), &Ws[buf][0] + dst);                 \
        async16(gW + ks64 + (k0), &Ws[buf][2048] + dst);       \
        async16(gW + 2 * ks64 + (k0), &Ws[buf][4096] + dst);   \
        async16(gW + 3 * ks64 + (k0), &Ws[buf][6144] + dst);

    STAGE_W(0, 0);
    __syncthreads();                       // drains vmcnt(0): tile 0 ready

    for (int tt = 0; tt < nkt; ++tt) {
        const int cur = tt & 1;
        if (tt + 1 < nkt) { STAGE_W(cur ^ 1, (tt + 1) * 32); }
        bf16x8 af[4], wf[8];
        #pragma unroll
        for (int i = 0; i < 4; i++)
            af[i] = *(const bf16x8*)(&As[cur][0] + (wrow + i * 16 + lrow) * 32 + kg);
        #pragma unroll
        for (int j = 0; j < 8; j++)
            wf[j] = *(const bf16x8*)(&Ws[cur][0] + (wcol + j * 16 + lrow) * 32 + kg);
        __builtin_amdgcn_s_setprio(1);
        #pragma unroll
        for (int i = 0; i < 4; i++)
            #pragma unroll
            for (int j = 0; j < 8; j++)
                acc[i][j] = __builtin_amdgcn_mfma_f32_16x16x32_bf16(
                    af[i], wf[j], acc[i][j], 0, 0, 0);
        __builtin_amdgcn_s_setprio(0);
        __syncthreads();                   // full drain publishes tile tt+1
    }
    #undef STAGE_W

    // ---- epilogue: 8 passes of 16 rows x 256 f32 (16 KiB) through LDS ------
    float* ldsf = (float*)&As[0][0];
    const int lcol = lane & 15;
    const int rb = (lane >> 4) * 4;
    #pragma unroll
    for (int p = 0; p < 8; p++) {
        __syncthreads();
        if ((wv >> 1) == (p >> 2)) {       // waves owning this 16-row stripe
            const int fi = p & 3;
            #pragma unroll
            for (int j = 0; j < 8; j++) {
                f32x4 v = acc[fi][j];
                int col = wcol + j * 16 + lcol;
                #pragma unroll
                for (int r2 = 0; r2 < 4; r2++) {
                    int row = rb + r2;     // 0..15 within stripe
                    ldsf[row * 256 + (col ^ ((row & 12) << 1))] = v[r2];
                }
            }
        }
        __syncthreads();
        #pragma unroll
        for (int it = 0; it < 4; it++) {
            int cch = it * 256 + t;        // 0..1023 chunks of 16B
            int row = cch >> 6, ch = cch & 63;
            f32x4 v = *(const f32x4*)(ldsf + row * 256
                                      + ((ch ^ ((row & 12) >> 1)) << 2));
            int grow = brow + p * 16 + row;
            int gcol = bcol + ch * 4;
            float* dstp = C + (size_t)grow * ldo + gcol;
            if (gcol + 4 <= Nstore) {
                *(f32x4*)dstp = v;
            } else {
                #pragma unroll
                for (int k2 = 0; k2 < 4; k2++)
                    if (gcol + k2 < Nstore) dstp[k2] = v[k2];
            }
        }
    }
}

// ---------------- bf16 MFMA GEMM (128^2, m97 structure) for small GEMMs -----
__global__ __launch_bounds__(256) void gemm_bt(
    const bf16* __restrict__ A, const bf16* __restrict__ W,
    const float* __restrict__ bias,
    float* __restrict__ outF, bf16* __restrict__ outB,
    int M, int K, int ldo, int Nstore, int relu)
{
    __shared__ bf16 As[BM * BK];
    __shared__ bf16 Ws[BN * BK];
    const int brow = blockIdx.y * BM;
    const int bcol = blockIdx.x * BN;
    const int t = threadIdx.x;
    const int wv = t >> 6;
    const int lane = t & 63;
    const int wrow = (wv >> 1) * 64;
    const int wcol = (wv & 1) * 64;

    f32x4 acc[4][4] = {};

    const int row0 = t >> 2;
    const int cg = (t & 3) * 8;
    const bf16* gA = A + (size_t)(brow + row0) * K + cg;
    const bf16* gW = W + (size_t)(bcol + row0) * K + cg;
    const size_t rstep = (size_t)64 * K;
    bf16* lA0 = As + wv * 512;
    bf16* lA1 = As + 2048 + wv * 512;
    bf16* lW0 = Ws + wv * 512;
    bf16* lW1 = Ws + 2048 + wv * 512;

    const int lrow = lane & 15;
    const int kg = (lane >> 4) * 8;

    for (int k0 = 0; k0 < K; k0 += BK) {
        if (k0) __syncthreads();
        async16(gA + k0, lA0);
        async16(gA + rstep + k0, lA1);
        async16(gW + k0, lW0);
        async16(gW + rstep + k0, lW1);
        __syncthreads();
        bf16x8 af[4], wf[4];
        #pragma unroll
        for (int i = 0; i < 4; i++)
            af[i] = *(const bf16x8*)(As + (wrow + i * 16 + lrow) * BK + kg);
        #pragma unroll
        for (int j = 0; j < 4; j++)
            wf[j] = *(const bf16x8*)(Ws + (wcol + j * 16 + lrow) * BK + kg);
        #pragma unroll
        for (int i = 0; i < 4; i++)
            #pragma unroll
            for (int j = 0; j < 4; j++)
                acc[i][j] = __builtin_amdgcn_mfma_f32_16x16x32_bf16(
                    af[i], wf[j], acc[i][j], 0, 0, 0);
    }

    const int lcol = lane & 15;
    const int rb = (lane >> 4) * 4;
    #pragma unroll
    for (int j = 0; j < 4; j++) {
        int n = bcol + wcol + j * 16 + lcol;
        if (n >= Nstore) continue;
        float bv = bias ? bias[n] : 0.f;
        #pragma unroll
        for (int i = 0; i < 4; i++) {
            #pragma unroll
            for (int r = 0; r < 4; r++) {
                int m = brow + wrow + i * 16 + rb + r;
                float v = acc[i][j][r] + bv;
                if (relu) v = fmaxf(v, 0.f);
                size_t off = (size_t)m * ldo + n;
                if (outF) outF[off] = v;
                if (outB) outB[off] = (bf16)v;
            }
        }
    }
}

// ---------------- fp32 -> bf16 convert (zero-pads rows beyond nvalid) --------
// Non-temporal source reads: big weights (proj_w = 159MB) are read ONCE.
__global__ __launch_bounds__(256) void cvt_bf16(
    const float* __restrict__ in, bf16* __restrict__ out,
    size_t nvalid, size_t ntotal)
{
    size_t i = ((size_t)blockIdx.x * 256 + threadIdx.x) * 4;
    if (i >= ntotal) return;
    bf16x4 r;
    if (i < nvalid) {
        f32x4 f = __builtin_nontemporal_load((const f32x4*)(in + i));
        r[0] = (bf16)f[0]; r[1] = (bf16)f[1]; r[2] = (bf16)f[2]; r[3] = (bf16)f[3];
    } else {
        r[0] = (bf16)0.f; r[1] = (bf16)0.f; r[2] = (bf16)0.f; r[3] = (bf16)0.f;
    }
    *(bf16x4*)(out + i) = r;
}

// ---------------- build tgt = [start, emb[tok0], emb[tok1]] per sequence -----
__global__ __launch_bounds__(256) void build_tgt(
    const float* __restrict__ start, const float* __restrict__ emb,
    const int* __restrict__ toks, float* __restrict__ outF, bf16* __restrict__ outB)
{
    int r = blockIdx.x;               // 0..3071, r = n*3 + p
    int n = r / 3, p = r % 3;
    const float* src = (p == 0) ? start : emb + (size_t)toks[n * 3 + (p - 1)] * 768;
    int t = threadIdx.x;
    #pragma unroll
    for (int j = 0; j < 3; j++) {
        int c = t + j * 256;
        float v = src[c];
        outF[(size_t)r * 768 + c] = v;
        outB[(size_t)r * 768 + c] = (bf16)v;
    }
}

// ---------------- 3-token causal self-attention, one wave per (n,head) -------
__global__ __launch_bounds__(64) void attn3(
    const float* __restrict__ qkv, bf16* __restrict__ o)
{
    int blk = blockIdx.x;             // n*4 + h
    int n = blk >> 2, h = blk & 3;
    int lane = threadIdx.x;
    const float* base = qkv + (size_t)n * 3 * 2304 + h * 192;
    float q[3][3], k[3][3], v[3][3];
    #pragma unroll
    for (int p = 0; p < 3; p++)
        #pragma unroll
        for (int j = 0; j < 3; j++) {
            int d = lane + j * 64;
            q[p][j] = base[p * 2304 + d];
            k[p][j] = base[p * 2304 + 768 + d];
            v[p][j] = base[p * 2304 + 1536 + d];
        }
    float s[3][3];
    #pragma unroll
    for (int p = 0; p < 3; p++)
        #pragma unroll
        for (int pk = 0; pk < 3; pk++) {
            if (pk > p) continue;
            float ps = q[p][0] * k[pk][0] + q[p][1] * k[pk][1] + q[p][2] * k[pk][2];
            #pragma unroll
            for (int off = 32; off; off >>= 1) ps += __shfl_xor(ps, off);
            s[p][pk] = ps * 0.072168783648703220563f;   // 1/sqrt(192)
        }
    float a[3][3] = {};
    a[0][0] = 1.f;
    {
        float m = fmaxf(s[1][0], s[1][1]);
        float e0 = expf(s[1][0] - m), e1 = expf(s[1][1] - m);
        float inv = 1.f / (e0 + e1);
        a[1][0] = e0 * inv; a[1][1] = e1 * inv;
    }
    {
        float m = fmaxf(fmaxf(s[2][0], s[2][1]), s[2][2]);
        float e0 = expf(s[2][0] - m), e1 = expf(s[2][1] - m), e2 = expf(s[2][2] - m);
        float inv = 1.f / (e0 + e1 + e2);
        a[2][0] = e0 * inv; a[2][1] = e1 * inv; a[2][2] = e2 * inv;
    }
    bf16* ob = o + (size_t)n * 3 * 768 + h * 192;
    #pragma unroll
    for (int p = 0; p < 3; p++)
        #pragma unroll
        for (int j = 0; j < 3; j++) {
            float val = a[p][0] * v[0][j];
            if (p >= 1) val += a[p][1] * v[1][j];
            if (p >= 2) val += a[p][2] * v[2][j];
            ob[p * 768 + lane + j * 64] = (bf16)val;
        }
}

// ---------------- x = LN(a + b) ; b optionally broadcast over 3 positions ----
__global__ __launch_bounds__(256) void add_ln(
    const float* __restrict__ a, const float* __restrict__ b,
    const float* __restrict__ g, const float* __restrict__ be,
    float* __restrict__ outF, bf16* __restrict__ outB, int bcast)
{
    int r = blockIdx.x;
    int t = threadIdx.x;
    const float* ar = a + (size_t)r * 768;
    const float* br = b + (size_t)(bcast ? (r / 3) : r) * 768;
    float x[3];
    float s = 0.f, sq = 0.f;
    #pragma unroll
    for (int j = 0; j < 3; j++) {
        int c = t + j * 256;
        x[j] = ar[c] + br[c];
        s += x[j]; sq += x[j] * x[j];
    }
    #pragma unroll
    for (int off = 32; off; off >>= 1) {
        s += __shfl_xor(s, off);
        sq += __shfl_xor(sq, off);
    }
    __shared__ float ls[4], lq[4];
    int wv = t >> 6;
    if ((t & 63) == 0) { ls[wv] = s; lq[wv] = sq; }
    __syncthreads();
    s = ls[0] + ls[1] + ls[2] + ls[3];
    sq = lq[0] + lq[1] + lq[2] + lq[3];
    float mean = s * (1.f / 768.f);
    float var = sq * (1.f / 768.f) - mean * mean;
    float inv = rsqrtf(var + 1e-5f);
    #pragma unroll
    for (int j = 0; j < 3; j++) {
        int c = t + j * 256;
        float y = (x[j] - mean) * inv * g[c] + be[c];
        if (outF) outF[(size_t)r * 768 + c] = y;
        if (outB) outB[(size_t)r * 768 + c] = (bf16)y;
    }
}

// =============================================================================
static inline void run_gemm(const bf16* A, const bf16* W, const float* bias,
                            float* outF, bf16* outB, int M, int Npad, int K,
                            int ldo, int Nstore, int relu, hipStream_t s)
{
    dim3 grid(Npad / BN, M / BM);
    gemm_bt<<<grid, 256, 0, s>>>(A, W, bias, outF, outB, M, K, ldo, Nstore, relu);
}

static inline void run_cvt(const float* in, bf16* out, size_t nvalid,
                           size_t ntotal, hipStream_t s)
{
    int blocks = (int)((ntotal / 4 + 255) / 256);
    cvt_bf16<<<blocks, 256, 0, s>>>(in, out, nvalid, ntotal);
}

extern "C" void kernel_launch(void* const* d_in, const int* in_sizes, int n_in,
                              void* d_out, int out_size, void* d_ws, size_t ws_size,
                              hipStream_t stream)
{
    const float* enc      = (const float*)d_in[0];   // (1024, 768)
    const int*   toks     = (const int*)d_in[1];     // (1024, 3)
    const float* start    = (const float*)d_in[2];   // (1, 768)
    const float* emb      = (const float*)d_in[3];   // (51865, 768)
    const float* sa_in_w  = (const float*)d_in[4];   // (2304, 768)
    const float* sa_in_b  = (const float*)d_in[5];
    const float* sa_out_w = (const float*)d_in[6];   // (768, 768)
    const float* sa_out_b = (const float*)d_in[7];
    const float* ca_in_w  = (const float*)d_in[8];   // (2304, 768); only Wv used
    const float* ca_in_b  = (const float*)d_in[9];
    const float* ca_out_w = (const float*)d_in[10];  // (768, 768)
    const float* ca_out_b = (const float*)d_in[11];
    const float* lin1_w   = (const float*)d_in[12];  // (2048, 768)
    const float* lin1_b   = (const float*)d_in[13];
    const float* lin2_w   = (const float*)d_in[14];  // (768, 2048)
    const float* lin2_b   = (const float*)d_in[15];
    const float* ln1_g    = (const float*)d_in[16];
    const float* ln1_bb   = (const float*)d_in[17];
    const float* ln2_g    = (const float*)d_in[18];
    const float* ln2_bb   = (const float*)d_in[19];
    const float* ln3_g    = (const float*)d_in[20];
    const float* ln3_bb   = (const float*)d_in[21];
    const float* proj_w   = (const float*)d_in[22];  // (51865, 768)
    float* out = (float*)d_out;

    const int NTOK = 3072;          // B*T*NT
    const int NM   = 1024;          // B*T
    const int H    = 768;
    const int V    = 51865;
    const int VPAD = 51968;         // 203*256
    const int DFF  = 2048;

    char* p = (char*)d_ws;
    auto alloc = [&](size_t bytes) {
        void* r = (void*)p;
        p += (bytes + 255) & ~(size_t)255;
        return r;
    };
    float* tgt_f = (float*)alloc((size_t)NTOK * H * 4);
    float* x1_f  = (float*)alloc((size_t)NTOK * H * 4);
    float* x2_f  = (float*)alloc((size_t)NTOK * H * 4);
    float* big_f = (float*)alloc((size_t)NTOK * 2304 * 4);  // qkv / gemm fp32 outs
    bf16*  actA  = (bf16*)alloc((size_t)NTOK * 2304 * 2);   // bf16 activations A
    bf16*  actB  = (bf16*)alloc((size_t)NTOK * DFF * 2);    // bf16 activations B
    bf16*  Wbf   = (bf16*)alloc((size_t)VPAD * H * 2);      // bf16 weights (reused)
    bf16*  mem_bf = actB;                                   // (1024,768) carved
    bf16*  v_bf   = actB + (size_t)NM * H;                  // (1024,768) carved
    float* cao_f  = big_f + (size_t)NTOK * H;               // (1024,768) carved

    // 1. tgt = [start, emb[t0], emb[t1]]
    build_tgt<<<NTOK, 256, 0, stream>>>(start, emb, toks, tgt_f, actA);

    // 2. qkv = tgt @ sa_in_w.T + b       (3072 x 2304)
    run_cvt(sa_in_w, Wbf, (size_t)2304 * H, (size_t)2304 * H, stream);
    run_gemm(actA, Wbf, sa_in_b, big_f, nullptr, NTOK, 2304, H, 2304, 2304, 0, stream);

    // 3. 3x3 causal attention -> o (bf16)
    attn3<<<NM * 4, 64, 0, stream>>>(big_f, actA);

    // 4. sa = o @ sa_out_w.T + b
    run_cvt(sa_out_w, Wbf, (size_t)H * H, (size_t)H * H, stream);
    run_gemm(actA, Wbf, sa_out_b, big_f, nullptr, NTOK, H, H, H, H, 0, stream);

    // 5. x1 = LN1(tgt + sa)
    add_ln<<<NTOK, 256, 0, stream>>>(tgt_f, big_f, ln1_g, ln1_bb, x1_f, nullptr, 0);

    // 6. cross-attn (Lk=1 => softmax==1 => output == V projection of memory)
    run_cvt(enc, mem_bf, (size_t)NM * H, (size_t)NM * H, stream);
    run_cvt(ca_in_w + (size_t)1536 * H, Wbf, (size_t)H * H, (size_t)H * H, stream);
    run_gemm(mem_bf, Wbf, ca_in_b + 1536, nullptr, v_bf, NM, H, H, H, H, 0, stream);
    run_cvt(ca_out_w, Wbf, (size_t)H * H, (size_t)H * H, stream);
    run_gemm(v_bf, Wbf, ca_out_b, cao_f, nullptr, NM, H, H, H, H, 0, stream);

    // 7. x2 = LN2(x1 + ca_out[broadcast])
    add_ln<<<NTOK, 256, 0, stream>>>(x1_f, cao_f, ln2_g, ln2_bb, x2_f, actA, 1);

    // 8. ff1 = relu(x2 @ lin1_w.T + b)   (bf16 only)
    run_cvt(lin1_w, Wbf, (size_t)DFF * H, (size_t)DFF * H, stream);
    run_gemm(actA, Wbf, lin1_b, nullptr, actB, NTOK, DFF, H, DFF, DFF, 1, stream);

    // 9. ff2 = ff1 @ lin2_w.T + b        (K = 2048)
    run_cvt(lin2_w, Wbf, (size_t)H * DFF, (size_t)H * DFF, stream);
    run_gemm(actB, Wbf, lin2_b, big_f, nullptr, NTOK, H, DFF, H, H, 0, stream);

    // 10. x3 = LN3(x2 + ff2) -> bf16 only
    add_ln<<<NTOK, 256, 0, stream>>>(x2_f, big_f, ln3_g, ln3_bb, nullptr, actA, 0);

    // 11. logits = x3 @ proj_w.T  (3072 x 51865) -- 128x256 2-block/CU kernel
    run_cvt(proj_w, Wbf, (size_t)V * H, (size_t)VPAD * H, stream);
    {
        const int nTilesM = NTOK / 128;            // 24
        dim3 grid(nTilesM * (VPAD / 256));          // 24 * 203 = 4872
        gemmWide<<<grid, 256, 0, stream>>>(actA, Wbf, out, H, V, V, nTilesM);
    }
}

// Round 9
// 549.180 us; speedup vs baseline: 1.2669x; 1.2452x over previous
//
#include <hip/hip_runtime.h>

typedef __bf16 bf16;
typedef __bf16 bf16x4 __attribute__((ext_vector_type(4)));
typedef __bf16 bf16x8 __attribute__((ext_vector_type(8)));
typedef float f32x4 __attribute__((ext_vector_type(4)));

#define BM 128
#define BN 128
#define BK 32

// ---------------- async global->LDS (16B per lane) ----------------
__device__ __forceinline__ void async16(const void* g, void* l) {
    __builtin_amdgcn_global_load_lds(
        (__attribute__((address_space(1))) void*)g,
        (__attribute__((address_space(3))) void*)l,
        16, 0, 0);
}

// =============================================================================
// Proj GEMM: 256^2, BK=64, double-buffered, 8 waves. 4-phase/K-tile schedule
// with DEEP load slack: tile k+1's A staged at phase A of tile k, B at phase B
// -> loads land 2.5-3.5 phases (~1000-1400 cyc) before the single vmcnt(4)
// (R5-R8 lesson: 2-phase slack ~600cyc < HBM ~900cyc latency was the stall).
// Register-hold: A-quadrant (32 VGPR) spans 2 phases, full-B (32 VGPR) spans
// all 4 -> 24 ds_read_b128/tile/wave, conflict-free (chunk^row XOR swizzle).
// Race ledger: stage target = dbuf[(k+1)&1], last read at tile k-1 phase C/D,
// >=1 barrier before any stage issue of tile k+1. Epilogue: LDS-transpose
// (R4) + NON-TEMPORAL contiguous f32x4 stores (1KB/wave-instr: no RMW, no
// L2/L3 write-allocate pollution -> W/A panels stay cached).
// =============================================================================
__global__ __launch_bounds__(512, 2) void gemm8p(
    const bf16* __restrict__ A, const bf16* __restrict__ W,
    float* __restrict__ C, int K, int ldo, int Nstore, int nTilesM)
{
    __shared__ bf16 lds[2][32768];   // [dbuf][A 16384 | B 16384] = 128 KiB

    // bijective XCD swizzle (m204) + m-fastest ordering for W-panel L2 reuse
    int nwg = gridDim.x;
    int orig = blockIdx.x;
    int q = nwg >> 3, r = nwg & 7, xcd = orig & 7, local = orig >> 3;
    int wgid = (xcd < r ? xcd * (q + 1) : r * (q + 1) + (xcd - r) * q) + local;
    const int brow = (wgid % nTilesM) * 256;
    const int bcol = (wgid / nTilesM) * 256;

    const int t = threadIdx.x;
    const int wid = t >> 6, lane = t & 63;
    const int wm = wid >> 2, wn = wid & 3;
    const int l15 = lane & 15, l7 = lane & 7, lhi = lane >> 4;

    // staging source: 64-row units, 8 chunks/row, inverse-swizzled chunk
    const int lr = t >> 3;                 // 0..63
    const int cc = (t & 7) ^ (lr & 7);
    const bf16* gA = A + (size_t)(brow + lr) * K + cc * 8;
    const bf16* gW = W + (size_t)(bcol + lr) * K + cc * 8;
    const int dsto = wid * 512;            // wave-uniform LDS base (HW adds lane*16B)

    // fragment read constants (elements)
    const int kx0 = ((0 * 4 + lhi) ^ l7) * 8;
    const int kx1 = ((1 * 4 + lhi) ^ l7) * 8;
    const int abase = wm * 8192 + l15 * 64;
    const int bbase = 16384 + (wn >> 1) * 8192 + ((wn & 1) * 64 + l15) * 64;

    f32x4 acc[8][4] = {};
    const int nkt = K >> 6;                // 12 for K=768

    #define ST_A(dst, k0)                                             \
        async16(gA + (k0),                   (dst) + dsto);           \
        async16(gA + (size_t)64 * K + (k0),  (dst) + 4096 + dsto);    \
        async16(gA + (size_t)128 * K + (k0), (dst) + 8192 + dsto);    \
        async16(gA + (size_t)192 * K + (k0), (dst) + 12288 + dsto);
    #define ST_B(dst, k0)                                                     \
        async16(gW + (k0),                   (dst) + 16384 + dsto);           \
        async16(gW + (size_t)64 * K + (k0),  (dst) + 20480 + dsto);           \
        async16(gW + (size_t)128 * K + (k0), (dst) + 24576 + dsto);           \
        async16(gW + (size_t)192 * K + (k0), (dst) + 28672 + dsto);

    // prologue: stage tile 0 fully (8 loads)
    { ST_A(&lds[0][0], 0); ST_B(&lds[0][0], 0); }

    bf16x8 a[4][2], b[4][2];
    for (int kt = 0; kt < nkt; ++kt) {
        const bf16* cur = &lds[kt & 1][0];
        bf16* stg = &lds[(kt + 1) & 1][0];
        const int k1 = (kt + 1) << 6;
        const bool st = (kt + 1 < nkt);

        // ---- phase A: stage A(k+1); drain tile k; read A0+Ball; Q(0,0) ----
        if (st) { ST_A(stg, k1); }
        if (st) asm volatile("s_waitcnt vmcnt(4)" ::: "memory");
        else    asm volatile("s_waitcnt vmcnt(0)" ::: "memory");
        __builtin_amdgcn_s_barrier();
        #pragma unroll
        for (int fi = 0; fi < 4; fi++) {
            a[fi][0] = *(const bf16x8*)(cur + abase + fi * 1024 + kx0);
            a[fi][1] = *(const bf16x8*)(cur + abase + fi * 1024 + kx1);
        }
        #pragma unroll
        for (int fj = 0; fj < 4; fj++) {
            b[fj][0] = *(const bf16x8*)(cur + bbase + fj * 1024 + kx0);
            b[fj][1] = *(const bf16x8*)(cur + bbase + fj * 1024 + kx1);
        }
        __builtin_amdgcn_s_setprio(1);
        #pragma unroll
        for (int fi = 0; fi < 4; fi++)
            #pragma unroll
            for (int fj = 0; fj < 2; fj++) {
                f32x4 c0 = acc[fi][fj];
                c0 = __builtin_amdgcn_mfma_f32_16x16x32_bf16(a[fi][0], b[fj][0], c0, 0,0,0);
                c0 = __builtin_amdgcn_mfma_f32_16x16x32_bf16(a[fi][1], b[fj][1], c0, 0,0,0);
                acc[fi][fj] = c0;
            }
        __builtin_amdgcn_s_setprio(0);
        __builtin_amdgcn_s_barrier();

        // ---- phase B: stage B(k+1); Q(0,1) (regs only) ----
        if (st) { ST_B(stg, k1); }
        __builtin_amdgcn_s_setprio(1);
        #pragma unroll
        for (int fi = 0; fi < 4; fi++)
            #pragma unroll
            for (int fj = 2; fj < 4; fj++) {
                f32x4 c0 = acc[fi][fj];
                c0 = __builtin_amdgcn_mfma_f32_16x16x32_bf16(a[fi][0], b[fj][0], c0, 0,0,0);
                c0 = __builtin_amdgcn_mfma_f32_16x16x32_bf16(a[fi][1], b[fj][1], c0, 0,0,0);
                acc[fi][fj] = c0;
            }
        __builtin_amdgcn_s_setprio(0);
        __builtin_amdgcn_s_barrier();

        // ---- phase C: read A1; Q(1,0) ----
        #pragma unroll
        for (int fi = 0; fi < 4; fi++) {
            a[fi][0] = *(const bf16x8*)(cur + abase + 4096 + fi * 1024 + kx0);
            a[fi][1] = *(const bf16x8*)(cur + abase + 4096 + fi * 1024 + kx1);
        }
        __builtin_amdgcn_s_setprio(1);
        #pragma unroll
        for (int fi = 0; fi < 4; fi++)
            #pragma unroll
            for (int fj = 0; fj < 2; fj++) {
                f32x4 c0 = acc[4 + fi][fj];
                c0 = __builtin_amdgcn_mfma_f32_16x16x32_bf16(a[fi][0], b[fj][0], c0, 0,0,0);
                c0 = __builtin_amdgcn_mfma_f32_16x16x32_bf16(a[fi][1], b[fj][1], c0, 0,0,0);
                acc[4 + fi][fj] = c0;
            }
        __builtin_amdgcn_s_setprio(0);
        __builtin_amdgcn_s_barrier();   // all waves' cur-reads done before next stage

        // ---- phase D: Q(1,1) (regs only; no trailing barrier needed) ----
        __builtin_amdgcn_s_setprio(1);
        #pragma unroll
        for (int fi = 0; fi < 4; fi++)
            #pragma unroll
            for (int fj = 2; fj < 4; fj++) {
                f32x4 c0 = acc[4 + fi][fj];
                c0 = __builtin_amdgcn_mfma_f32_16x16x32_bf16(a[fi][0], b[fj][0], c0, 0,0,0);
                c0 = __builtin_amdgcn_mfma_f32_16x16x32_bf16(a[fi][1], b[fj][1], c0, 0,0,0);
                acc[4 + fi][fj] = c0;
            }
        __builtin_amdgcn_s_setprio(0);
    }
    #undef ST_A
    #undef ST_B

    // ---- epilogue: LDS transpose (XOR swizzle) -> contiguous NT f32x4 stores
    // Per-wave scatter regions are disjoint; last tile's reads ended at phase C
    // barrier, vmcnt(0) done at last phase A -> no leading barrier needed.
    float* ldsf = (float*)&lds[0][0];
    const int lhi4 = lhi * 4;
    #pragma unroll
    for (int h = 0; h < 2; h++) {
        if (h) __builtin_amdgcn_s_barrier();  // h0 gather reads done (per-wave
                                              // ds_reads complete before their
                                              // dependent stores issued)
        #pragma unroll
        for (int fi4 = 0; fi4 < 4; fi4++) {
            #pragma unroll
            for (int fj = 0; fj < 4; fj++) {
                f32x4 v = acc[h * 4 + fi4][fj];
                int row0 = wm * 64 + fi4 * 16 + lhi4;
                int col = wn * 64 + fj * 16 + l15;
                #pragma unroll
                for (int r2 = 0; r2 < 4; r2++) {
                    int row = row0 + r2;
                    ldsf[row * 256 + (col ^ ((row & 12) << 1))] = v[r2];
                }
            }
        }
        __builtin_amdgcn_s_barrier();
        #pragma unroll
        for (int i = 0; i < 16; i++) {
            int c = i * 512 + t;               // 0..8191 chunks of 16B
            int row = c >> 6, ch = c & 63;
            f32x4 v = *(const f32x4*)(ldsf + row * 256
                                      + ((ch ^ ((row & 12) >> 1)) << 2));
            int grow = brow + (row >> 6) * 128 + h * 64 + (row & 63);
            int gcol = bcol + ch * 4;
            float* dst = C + (size_t)grow * ldo + gcol;
            if (gcol + 4 <= Nstore) {
                __builtin_nontemporal_store(v, (f32x4*)dst);
            } else {
                #pragma unroll
                for (int k2 = 0; k2 < 4; k2++)
                    if (gcol + k2 < Nstore) dst[k2] = v[k2];
            }
        }
    }
}

// ---------------- bf16 MFMA GEMM (128^2, m97 structure) for small GEMMs -----
__global__ __launch_bounds__(256) void gemm_bt(
    const bf16* __restrict__ A, const bf16* __restrict__ W,
    const float* __restrict__ bias,
    float* __restrict__ outF, bf16* __restrict__ outB,
    int M, int K, int ldo, int Nstore, int relu)
{
    __shared__ bf16 As[BM * BK];
    __shared__ bf16 Ws[BN * BK];
    const int brow = blockIdx.y * BM;
    const int bcol = blockIdx.x * BN;
    const int t = threadIdx.x;
    const int wv = t >> 6;
    const int lane = t & 63;
    const int wrow = (wv >> 1) * 64;
    const int wcol = (wv & 1) * 64;

    f32x4 acc[4][4] = {};

    const int row0 = t >> 2;
    const int cg = (t & 3) * 8;
    const bf16* gA = A + (size_t)(brow + row0) * K + cg;
    const bf16* gW = W + (size_t)(bcol + row0) * K + cg;
    const size_t rstep = (size_t)64 * K;
    bf16* lA0 = As + wv * 512;
    bf16* lA1 = As + 2048 + wv * 512;
    bf16* lW0 = Ws + wv * 512;
    bf16* lW1 = Ws + 2048 + wv * 512;

    const int lrow = lane & 15;
    const int kg = (lane >> 4) * 8;

    for (int k0 = 0; k0 < K; k0 += BK) {
        if (k0) __syncthreads();
        async16(gA + k0, lA0);
        async16(gA + rstep + k0, lA1);
        async16(gW + k0, lW0);
        async16(gW + rstep + k0, lW1);
        __syncthreads();
        bf16x8 af[4], wf[4];
        #pragma unroll
        for (int i = 0; i < 4; i++)
            af[i] = *(const bf16x8*)(As + (wrow + i * 16 + lrow) * BK + kg);
        #pragma unroll
        for (int j = 0; j < 4; j++)
            wf[j] = *(const bf16x8*)(Ws + (wcol + j * 16 + lrow) * BK + kg);
        #pragma unroll
        for (int i = 0; i < 4; i++)
            #pragma unroll
            for (int j = 0; j < 4; j++)
                acc[i][j] = __builtin_amdgcn_mfma_f32_16x16x32_bf16(
                    af[i], wf[j], acc[i][j], 0, 0, 0);
    }

    const int lcol = lane & 15;
    const int rb = (lane >> 4) * 4;
    #pragma unroll
    for (int j = 0; j < 4; j++) {
        int n = bcol + wcol + j * 16 + lcol;
        if (n >= Nstore) continue;
        float bv = bias ? bias[n] : 0.f;
        #pragma unroll
        for (int i = 0; i < 4; i++) {
            #pragma unroll
            for (int r = 0; r < 4; r++) {
                int m = brow + wrow + i * 16 + rb + r;
                float v = acc[i][j][r] + bv;
                if (relu) v = fmaxf(v, 0.f);
                size_t off = (size_t)m * ldo + n;
                if (outF) outF[off] = v;
                if (outB) outB[off] = (bf16)v;
            }
        }
    }
}

// ---------------- fp32 -> bf16 convert (zero-pads rows beyond nvalid) --------
// Non-temporal source reads: big weights (proj_w = 159MB) are read ONCE.
__global__ __launch_bounds__(256) void cvt_bf16(
    const float* __restrict__ in, bf16* __restrict__ out,
    size_t nvalid, size_t ntotal)
{
    size_t i = ((size_t)blockIdx.x * 256 + threadIdx.x) * 4;
    if (i >= ntotal) return;
    bf16x4 r;
    if (i < nvalid) {
        f32x4 f = __builtin_nontemporal_load((const f32x4*)(in + i));
        r[0] = (bf16)f[0]; r[1] = (bf16)f[1]; r[2] = (bf16)f[2]; r[3] = (bf16)f[3];
    } else {
        r[0] = (bf16)0.f; r[1] = (bf16)0.f; r[2] = (bf16)0.f; r[3] = (bf16)0.f;
    }
    *(bf16x4*)(out + i) = r;
}

// ---------------- build tgt = [start, emb[tok0], emb[tok1]] per sequence -----
__global__ __launch_bounds__(256) void build_tgt(
    const float* __restrict__ start, const float* __restrict__ emb,
    const int* __restrict__ toks, float* __restrict__ outF, bf16* __restrict__ outB)
{
    int r = blockIdx.x;               // 0..3071, r = n*3 + p
    int n = r / 3, p = r % 3;
    const float* src = (p == 0) ? start : emb + (size_t)toks[n * 3 + (p - 1)] * 768;
    int t = threadIdx.x;
    #pragma unroll
    for (int j = 0; j < 3; j++) {
        int c = t + j * 256;
        float v = src[c];
        outF[(size_t)r * 768 + c] = v;
        outB[(size_t)r * 768 + c] = (bf16)v;
    }
}

// ---------------- 3-token causal self-attention, one wave per (n,head) -------
__global__ __launch_bounds__(64) void attn3(
    const float* __restrict__ qkv, bf16* __restrict__ o)
{
    int blk = blockIdx.x;             // n*4 + h
    int n = blk >> 2, h = blk & 3;
    int lane = threadIdx.x;
    const float* base = qkv + (size_t)n * 3 * 2304 + h * 192;
    float q[3][3], k[3][3], v[3][3];
    #pragma unroll
    for (int p = 0; p < 3; p++)
        #pragma unroll
        for (int j = 0; j < 3; j++) {
            int d = lane + j * 64;
            q[p][j] = base[p * 2304 + d];
            k[p][j] = base[p * 2304 + 768 + d];
            v[p][j] = base[p * 2304 + 1536 + d];
        }
    float s[3][3];
    #pragma unroll
    for (int p = 0; p < 3; p++)
        #pragma unroll
        for (int pk = 0; pk < 3; pk++) {
            if (pk > p) continue;
            float ps = q[p][0] * k[pk][0] + q[p][1] * k[pk][1] + q[p][2] * k[pk][2];
            #pragma unroll
            for (int off = 32; off; off >>= 1) ps += __shfl_xor(ps, off);
            s[p][pk] = ps * 0.072168783648703220563f;   // 1/sqrt(192)
        }
    float a[3][3] = {};
    a[0][0] = 1.f;
    {
        float m = fmaxf(s[1][0], s[1][1]);
        float e0 = expf(s[1][0] - m), e1 = expf(s[1][1] - m);
        float inv = 1.f / (e0 + e1);
        a[1][0] = e0 * inv; a[1][1] = e1 * inv;
    }
    {
        float m = fmaxf(fmaxf(s[2][0], s[2][1]), s[2][2]);
        float e0 = expf(s[2][0] - m), e1 = expf(s[2][1] - m), e2 = expf(s[2][2] - m);
        float inv = 1.f / (e0 + e1 + e2);
        a[2][0] = e0 * inv; a[2][1] = e1 * inv; a[2][2] = e2 * inv;
    }
    bf16* ob = o + (size_t)n * 3 * 768 + h * 192;
    #pragma unroll
    for (int p = 0; p < 3; p++)
        #pragma unroll
        for (int j = 0; j < 3; j++) {
            float val = a[p][0] * v[0][j];
            if (p >= 1) val += a[p][1] * v[1][j];
            if (p >= 2) val += a[p][2] * v[2][j];
            ob[p * 768 + lane + j * 64] = (bf16)val;
        }
}

// ---------------- x = LN(a + b) ; b optionally broadcast over 3 positions ----
__global__ __launch_bounds__(256) void add_ln(
    const float* __restrict__ a, const float* __restrict__ b,
    const float* __restrict__ g, const float* __restrict__ be,
    float* __restrict__ outF, bf16* __restrict__ outB, int bcast)
{
    int r = blockIdx.x;
    int t = threadIdx.x;
    const float* ar = a + (size_t)r * 768;
    const float* br = b + (size_t)(bcast ? (r / 3) : r) * 768;
    float x[3];
    float s = 0.f, sq = 0.f;
    #pragma unroll
    for (int j = 0; j < 3; j++) {
        int c = t + j * 256;
        x[j] = ar[c] + br[c];
        s += x[j]; sq += x[j] * x[j];
    }
    #pragma unroll
    for (int off = 32; off; off >>= 1) {
        s += __shfl_xor(s, off);
        sq += __shfl_xor(sq, off);
    }
    __shared__ float ls[4], lq[4];
    int wv = t >> 6;
    if ((t & 63) == 0) { ls[wv] = s; lq[wv] = sq; }
    __syncthreads();
    s = ls[0] + ls[1] + ls[2] + ls[3];
    sq = lq[0] + lq[1] + lq[2] + lq[3];
    float mean = s * (1.f / 768.f);
    float var = sq * (1.f / 768.f) - mean * mean;
    float inv = rsqrtf(var + 1e-5f);
    #pragma unroll
    for (int j = 0; j < 3; j++) {
        int c = t + j * 256;
        float y = (x[j] - mean) * inv * g[c] + be[c];
        if (outF) outF[(size_t)r * 768 + c] = y;
        if (outB) outB[(size_t)r * 768 + c] = (bf16)y;
    }
}

// =============================================================================
static inline void run_gemm(const bf16* A, const bf16* W, const float* bias,
                            float* outF, bf16* outB, int M, int Npad, int K,
                            int ldo, int Nstore, int relu, hipStream_t s)
{
    dim3 grid(Npad / BN, M / BM);
    gemm_bt<<<grid, 256, 0, s>>>(A, W, bias, outF, outB, M, K, ldo, Nstore, relu);
}

static inline void run_cvt(const float* in, bf16* out, size_t nvalid,
                           size_t ntotal, hipStream_t s)
{
    int blocks = (int)((ntotal / 4 + 255) / 256);
    cvt_bf16<<<blocks, 256, 0, s>>>(in, out, nvalid, ntotal);
}

extern "C" void kernel_launch(void* const* d_in, const int* in_sizes, int n_in,
                              void* d_out, int out_size, void* d_ws, size_t ws_size,
                              hipStream_t stream)
{
    const float* enc      = (const float*)d_in[0];   // (1024, 768)
    const int*   toks     = (const int*)d_in[1];     // (1024, 3)
    const float* start    = (const float*)d_in[2];   // (1, 768)
    const float* emb      = (const float*)d_in[3];   // (51865, 768)
    const float* sa_in_w  = (const float*)d_in[4];   // (2304, 768)
    const float* sa_in_b  = (const float*)d_in[5];
    const float* sa_out_w = (const float*)d_in[6];   // (768, 768)
    const float* sa_out_b = (const float*)d_in[7];
    const float* ca_in_w  = (const float*)d_in[8];   // (2304, 768); only Wv used
    const float* ca_in_b  = (const float*)d_in[9];
    const float* ca_out_w = (const float*)d_in[10];  // (768, 768)
    const float* ca_out_b = (const float*)d_in[11];
    const float* lin1_w   = (const float*)d_in[12];  // (2048, 768)
    const float* lin1_b   = (const float*)d_in[13];
    const float* lin2_w   = (const float*)d_in[14];  // (768, 2048)
    const float* lin2_b   = (const float*)d_in[15];
    const float* ln1_g    = (const float*)d_in[16];
    const float* ln1_bb   = (const float*)d_in[17];
    const float* ln2_g    = (const float*)d_in[18];
    const float* ln2_bb   = (const float*)d_in[19];
    const float* ln3_g    = (const float*)d_in[20];
    const float* ln3_bb   = (const float*)d_in[21];
    const float* proj_w   = (const float*)d_in[22];  // (51865, 768)
    float* out = (float*)d_out;

    const int NTOK = 3072;          // B*T*NT
    const int NM   = 1024;          // B*T
    const int H    = 768;
    const int V    = 51865;
    const int VPAD = 51968;         // 203*256
    const int DFF  = 2048;

    char* p = (char*)d_ws;
    auto alloc = [&](size_t bytes) {
        void* r = (void*)p;
        p += (bytes + 255) & ~(size_t)255;
        return r;
    };
    float* tgt_f = (float*)alloc((size_t)NTOK * H * 4);
    float* x1_f  = (float*)alloc((size_t)NTOK * H * 4);
    float* x2_f  = (float*)alloc((size_t)NTOK * H * 4);
    float* big_f = (float*)alloc((size_t)NTOK * 2304 * 4);  // qkv / gemm fp32 outs
    bf16*  actA  = (bf16*)alloc((size_t)NTOK * 2304 * 2);   // bf16 activations A
    bf16*  actB  = (bf16*)alloc((size_t)NTOK * DFF * 2);    // bf16 activations B
    bf16*  Wbf   = (bf16*)alloc((size_t)VPAD * H * 2);      // bf16 weights (reused)
    bf16*  mem_bf = actB;                                   // (1024,768) carved
    bf16*  v_bf   = actB + (size_t)NM * H;                  // (1024,768) carved
    float* cao_f  = big_f + (size_t)NTOK * H;               // (1024,768) carved

    // 1. tgt = [start, emb[t0], emb[t1]]
    build_tgt<<<NTOK, 256, 0, stream>>>(start, emb, toks, tgt_f, actA);

    // 2. qkv = tgt @ sa_in_w.T + b       (3072 x 2304)
    run_cvt(sa_in_w, Wbf, (size_t)2304 * H, (size_t)2304 * H, stream);
    run_gemm(actA, Wbf, sa_in_b, big_f, nullptr, NTOK, 2304, H, 2304, 2304, 0, stream);

    // 3. 3x3 causal attention -> o (bf16)
    attn3<<<NM * 4, 64, 0, stream>>>(big_f, actA);

    // 4. sa = o @ sa_out_w.T + b
    run_cvt(sa_out_w, Wbf, (size_t)H * H, (size_t)H * H, stream);
    run_gemm(actA, Wbf, sa_out_b, big_f, nullptr, NTOK, H, H, H, H, 0, stream);

    // 5. x1 = LN1(tgt + sa)
    add_ln<<<NTOK, 256, 0, stream>>>(tgt_f, big_f, ln1_g, ln1_bb, x1_f, nullptr, 0);

    // 6. cross-attn (Lk=1 => softmax==1 => output == V projection of memory)
    run_cvt(enc, mem_bf, (size_t)NM * H, (size_t)NM * H, stream);
    run_cvt(ca_in_w + (size_t)1536 * H, Wbf, (size_t)H * H, (size_t)H * H, stream);
    run_gemm(mem_bf, Wbf, ca_in_b + 1536, nullptr, v_bf, NM, H, H, H, H, 0, stream);
    run_cvt(ca_out_w, Wbf, (size_t)H * H, (size_t)H * H, stream);
    run_gemm(v_bf, Wbf, ca_out_b, cao_f, nullptr, NM, H, H, H, H, 0, stream);

    // 7. x2 = LN2(x1 + ca_out[broadcast])
    add_ln<<<NTOK, 256, 0, stream>>>(x1_f, cao_f, ln2_g, ln2_bb, x2_f, actA, 1);

    // 8. ff1 = relu(x2 @ lin1_w.T + b)   (bf16 only)
    run_cvt(lin1_w, Wbf, (size_t)DFF * H, (size_t)DFF * H, stream);
    run_gemm(actA, Wbf, lin1_b, nullptr, actB, NTOK, DFF, H, DFF, DFF, 1, stream);

    // 9. ff2 = ff1 @ lin2_w.T + b        (K = 2048)
    run_cvt(lin2_w, Wbf, (size_t)H * DFF, (size_t)H * DFF, stream);
    run_gemm(actB, Wbf, lin2_b, big_f, nullptr, NTOK, H, DFF, H, H, 0, stream);

    // 10. x3 = LN3(x2 + ff2) -> bf16 only
    add_ln<<<NTOK, 256, 0, stream>>>(x2_f, big_f, ln3_g, ln3_bb, nullptr, actA, 0);

    // 11. logits = x3 @ proj_w.T  (3072 x 51865) -- deep-slack 4-phase kernel
    run_cvt(proj_w, Wbf, (size_t)V * H, (size_t)VPAD * H, stream);
    {
        dim3 grid((NTOK / 256) * (VPAD / 256));   // 12 * 203 = 2436
        gemm8p<<<grid, 512, 0, stream>>>(actA, Wbf, out, H, V, V, NTOK / 256);
    }
}

// Round 10
// 546.696 us; speedup vs baseline: 1.2726x; 1.0045x over previous
//
#include <hip/hip_runtime.h>

typedef __bf16 bf16;
typedef __bf16 bf16x4 __attribute__((ext_vector_type(4)));
typedef __bf16 bf16x8 __attribute__((ext_vector_type(8)));
typedef float f32x4 __attribute__((ext_vector_type(4)));

#define BM 128
#define BN 128
#define BK 32

// ---------------- async global->LDS (16B per lane) ----------------
__device__ __forceinline__ void async16(const void* g, void* l) {
    __builtin_amdgcn_global_load_lds(
        (__attribute__((address_space(1))) void*)g,
        (__attribute__((address_space(3))) void*)l,
        16, 0, 0);
}

// =============================================================================
// Proj GEMM: 256^2, BK=64, double-buffered, 8 waves, deep load slack (R9 win).
// R10: barrier count 4 -> 2 per K-tile. Ledger: (1) top barrier after vmcnt
// publishes tile k (needed). (2) mid barrier after A1-consuming MFMAs: last
// reads of cur complete before it; next tile's ST_A (targeting this buffer)
// issues after it -> 1-barrier separation (sufficient: barrier = all waves
// passed, reads were consumed by pre-barrier MFMAs). Removed A->B, B->C
// barriers: their stage targets' last readers are >=1 barrier upstream.
// ST_B issues before the first MFMA cluster (more slack). vmcnt(4) FIFO:
// at tile-k top, outstanding = A(k)[4]+B(k)[4]+A(k+1)[4]=12 -> drains
// A(k),B(k), leaves A(k+1). Epilogue: LDS-transpose + NT contiguous stores.
// =============================================================================
__global__ __launch_bounds__(512, 2) void gemm8p(
    const bf16* __restrict__ A, const bf16* __restrict__ W,
    float* __restrict__ C, int K, int ldo, int Nstore, int nTilesM)
{
    __shared__ bf16 lds[2][32768];   // [dbuf][A 16384 | B 16384] = 128 KiB

    // bijective XCD swizzle (m204) + m-fastest ordering for W-panel L2 reuse
    int nwg = gridDim.x;
    int orig = blockIdx.x;
    int q = nwg >> 3, r = nwg & 7, xcd = orig & 7, local = orig >> 3;
    int wgid = (xcd < r ? xcd * (q + 1) : r * (q + 1) + (xcd - r) * q) + local;
    const int brow = (wgid % nTilesM) * 256;
    const int bcol = (wgid / nTilesM) * 256;

    const int t = threadIdx.x;
    const int wid = t >> 6, lane = t & 63;
    const int wm = wid >> 2, wn = wid & 3;
    const int l15 = lane & 15, l7 = lane & 7, lhi = lane >> 4;

    // staging source: 64-row units, 8 chunks/row, inverse-swizzled chunk
    const int lr = t >> 3;                 // 0..63
    const int cc = (t & 7) ^ (lr & 7);
    const bf16* gA = A + (size_t)(brow + lr) * K + cc * 8;
    const bf16* gW = W + (size_t)(bcol + lr) * K + cc * 8;
    const int dsto = wid * 512;            // wave-uniform LDS base (HW adds lane*16B)

    // fragment read constants (elements)
    const int kx0 = ((0 * 4 + lhi) ^ l7) * 8;
    const int kx1 = ((1 * 4 + lhi) ^ l7) * 8;
    const int abase = wm * 8192 + l15 * 64;
    const int bbase = 16384 + (wn >> 1) * 8192 + ((wn & 1) * 64 + l15) * 64;

    f32x4 acc[8][4] = {};
    const int nkt = K >> 6;                // 12 for K=768

    #define ST_A(dst, k0)                                             \
        async16(gA + (k0),                   (dst) + dsto);           \
        async16(gA + (size_t)64 * K + (k0),  (dst) + 4096 + dsto);    \
        async16(gA + (size_t)128 * K + (k0), (dst) + 8192 + dsto);    \
        async16(gA + (size_t)192 * K + (k0), (dst) + 12288 + dsto);
    #define ST_B(dst, k0)                                                     \
        async16(gW + (k0),                   (dst) + 16384 + dsto);           \
        async16(gW + (size_t)64 * K + (k0),  (dst) + 20480 + dsto);           \
        async16(gW + (size_t)128 * K + (k0), (dst) + 24576 + dsto);           \
        async16(gW + (size_t)192 * K + (k0), (dst) + 28672 + dsto);

    // prologue: stage tile 0 fully (8 loads)
    { ST_A(&lds[0][0], 0); ST_B(&lds[0][0], 0); }

    bf16x8 a[4][2], b[4][2];
    for (int kt = 0; kt < nkt; ++kt) {
        const bf16* cur = &lds[kt & 1][0];
        bf16* stg = &lds[(kt + 1) & 1][0];
        const int k1 = (kt + 1) << 6;
        const bool st = (kt + 1 < nkt);

        // ---- half 1: stage A(k+1); drain tile k; read A0+B; stage B(k+1);
        //      32 MFMA Q(0,*) ----
        if (st) { ST_A(stg, k1); }
        if (st) asm volatile("s_waitcnt vmcnt(4)" ::: "memory");
        else    asm volatile("s_waitcnt vmcnt(0)" ::: "memory");
        __builtin_amdgcn_s_barrier();
        #pragma unroll
        for (int fi = 0; fi < 4; fi++) {
            a[fi][0] = *(const bf16x8*)(cur + abase + fi * 1024 + kx0);
            a[fi][1] = *(const bf16x8*)(cur + abase + fi * 1024 + kx1);
        }
        #pragma unroll
        for (int fj = 0; fj < 4; fj++) {
            b[fj][0] = *(const bf16x8*)(cur + bbase + fj * 1024 + kx0);
            b[fj][1] = *(const bf16x8*)(cur + bbase + fj * 1024 + kx1);
        }
        if (st) { ST_B(stg, k1); }
        __builtin_amdgcn_s_setprio(1);
        #pragma unroll
        for (int fi = 0; fi < 4; fi++)
            #pragma unroll
            for (int fj = 0; fj < 4; fj++) {
                f32x4 c0 = acc[fi][fj];
                c0 = __builtin_amdgcn_mfma_f32_16x16x32_bf16(a[fi][0], b[fj][0], c0, 0,0,0);
                c0 = __builtin_amdgcn_mfma_f32_16x16x32_bf16(a[fi][1], b[fj][1], c0, 0,0,0);
                acc[fi][fj] = c0;
            }
        __builtin_amdgcn_s_setprio(0);

        // ---- half 2: read A1; 16 MFMA Q(1,0..1); barrier (all cur reads
        //      consumed); 16 MFMA Q(1,2..3) reg-only ----
        #pragma unroll
        for (int fi = 0; fi < 4; fi++) {
            a[fi][0] = *(const bf16x8*)(cur + abase + 4096 + fi * 1024 + kx0);
            a[fi][1] = *(const bf16x8*)(cur + abase + 4096 + fi * 1024 + kx1);
        }
        __builtin_amdgcn_s_setprio(1);
        #pragma unroll
        for (int fi = 0; fi < 4; fi++)
            #pragma unroll
            for (int fj = 0; fj < 2; fj++) {
                f32x4 c0 = acc[4 + fi][fj];
                c0 = __builtin_amdgcn_mfma_f32_16x16x32_bf16(a[fi][0], b[fj][0], c0, 0,0,0);
                c0 = __builtin_amdgcn_mfma_f32_16x16x32_bf16(a[fi][1], b[fj][1], c0, 0,0,0);
                acc[4 + fi][fj] = c0;
            }
        __builtin_amdgcn_s_setprio(0);
        __builtin_amdgcn_s_barrier();   // cur reads done; next ST_A may overwrite
        __builtin_amdgcn_s_setprio(1);
        #pragma unroll
        for (int fi = 0; fi < 4; fi++)
            #pragma unroll
            for (int fj = 2; fj < 4; fj++) {
                f32x4 c0 = acc[4 + fi][fj];
                c0 = __builtin_amdgcn_mfma_f32_16x16x32_bf16(a[fi][0], b[fj][0], c0, 0,0,0);
                c0 = __builtin_amdgcn_mfma_f32_16x16x32_bf16(a[fi][1], b[fj][1], c0, 0,0,0);
                acc[4 + fi][fj] = c0;
            }
        __builtin_amdgcn_s_setprio(0);
    }
    #undef ST_A
    #undef ST_B

    // ---- epilogue: LDS transpose (XOR swizzle) -> contiguous NT f32x4 stores
    // lds[0] last read at tile nkt-2 (>=2 barriers upstream) -> safe for h=0.
    float* ldsf = (float*)&lds[0][0];
    const int lhi4 = lhi * 4;
    #pragma unroll
    for (int h = 0; h < 2; h++) {
        if (h) __builtin_amdgcn_s_barrier();  // h0 gather reads consumed
        #pragma unroll
        for (int fi4 = 0; fi4 < 4; fi4++) {
            #pragma unroll
            for (int fj = 0; fj < 4; fj++) {
                f32x4 v = acc[h * 4 + fi4][fj];
                int row0 = wm * 64 + fi4 * 16 + lhi4;
                int col = wn * 64 + fj * 16 + l15;
                #pragma unroll
                for (int r2 = 0; r2 < 4; r2++) {
                    int row = row0 + r2;
                    ldsf[row * 256 + (col ^ ((row & 12) << 1))] = v[r2];
                }
            }
        }
        __builtin_amdgcn_s_barrier();
        #pragma unroll
        for (int i = 0; i < 16; i++) {
            int c = i * 512 + t;               // 0..8191 chunks of 16B
            int row = c >> 6, ch = c & 63;
            f32x4 v = *(const f32x4*)(ldsf + row * 256
                                      + ((ch ^ ((row & 12) >> 1)) << 2));
            int grow = brow + (row >> 6) * 128 + h * 64 + (row & 63);
            int gcol = bcol + ch * 4;
            float* dst = C + (size_t)grow * ldo + gcol;
            if (gcol + 4 <= Nstore) {
                __builtin_nontemporal_store(v, (f32x4*)dst);
            } else {
                #pragma unroll
                for (int k2 = 0; k2 < 4; k2++)
                    if (gcol + k2 < Nstore) dst[k2] = v[k2];
            }
        }
    }
}

// ---------------- bf16 MFMA GEMM (128^2, m97 structure) for small GEMMs -----
__global__ __launch_bounds__(256) void gemm_bt(
    const bf16* __restrict__ A, const bf16* __restrict__ W,
    const float* __restrict__ bias,
    float* __restrict__ outF, bf16* __restrict__ outB,
    int M, int K, int ldo, int Nstore, int relu)
{
    __shared__ bf16 As[BM * BK];
    __shared__ bf16 Ws[BN * BK];
    const int brow = blockIdx.y * BM;
    const int bcol = blockIdx.x * BN;
    const int t = threadIdx.x;
    const int wv = t >> 6;
    const int lane = t & 63;
    const int wrow = (wv >> 1) * 64;
    const int wcol = (wv & 1) * 64;

    f32x4 acc[4][4] = {};

    const int row0 = t >> 2;
    const int cg = (t & 3) * 8;
    const bf16* gA = A + (size_t)(brow + row0) * K + cg;
    const bf16* gW = W + (size_t)(bcol + row0) * K + cg;
    const size_t rstep = (size_t)64 * K;
    bf16* lA0 = As + wv * 512;
    bf16* lA1 = As + 2048 + wv * 512;
    bf16* lW0 = Ws + wv * 512;
    bf16* lW1 = Ws + 2048 + wv * 512;

    const int lrow = lane & 15;
    const int kg = (lane >> 4) * 8;

    for (int k0 = 0; k0 < K; k0 += BK) {
        if (k0) __syncthreads();
        async16(gA + k0, lA0);
        async16(gA + rstep + k0, lA1);
        async16(gW + k0, lW0);
        async16(gW + rstep + k0, lW1);
        __syncthreads();
        bf16x8 af[4], wf[4];
        #pragma unroll
        for (int i = 0; i < 4; i++)
            af[i] = *(const bf16x8*)(As + (wrow + i * 16 + lrow) * BK + kg);
        #pragma unroll
        for (int j = 0; j < 4; j++)
            wf[j] = *(const bf16x8*)(Ws + (wcol + j * 16 + lrow) * BK + kg);
        #pragma unroll
        for (int i = 0; i < 4; i++)
            #pragma unroll
            for (int j = 0; j < 4; j++)
                acc[i][j] = __builtin_amdgcn_mfma_f32_16x16x32_bf16(
                    af[i], wf[j], acc[i][j], 0, 0, 0);
    }

    const int lcol = lane & 15;
    const int rb = (lane >> 4) * 4;
    #pragma unroll
    for (int j = 0; j < 4; j++) {
        int n = bcol + wcol + j * 16 + lcol;
        if (n >= Nstore) continue;
        float bv = bias ? bias[n] : 0.f;
        #pragma unroll
        for (int i = 0; i < 4; i++) {
            #pragma unroll
            for (int r = 0; r < 4; r++) {
                int m = brow + wrow + i * 16 + rb + r;
                float v = acc[i][j][r] + bv;
                if (relu) v = fmaxf(v, 0.f);
                size_t off = (size_t)m * ldo + n;
                if (outF) outF[off] = v;
                if (outB) outB[off] = (bf16)v;
            }
        }
    }
}

// ---------------- fp32 -> bf16 convert (zero-pads rows beyond nvalid) --------
// Non-temporal source reads: big weights (proj_w = 159MB) are read ONCE.
__global__ __launch_bounds__(256) void cvt_bf16(
    const float* __restrict__ in, bf16* __restrict__ out,
    size_t nvalid, size_t ntotal)
{
    size_t i = ((size_t)blockIdx.x * 256 + threadIdx.x) * 4;
    if (i >= ntotal) return;
    bf16x4 r;
    if (i < nvalid) {
        f32x4 f = __builtin_nontemporal_load((const f32x4*)(in + i));
        r[0] = (bf16)f[0]; r[1] = (bf16)f[1]; r[2] = (bf16)f[2]; r[3] = (bf16)f[3];
    } else {
        r[0] = (bf16)0.f; r[1] = (bf16)0.f; r[2] = (bf16)0.f; r[3] = (bf16)0.f;
    }
    *(bf16x4*)(out + i) = r;
}

// ---------------- build tgt = [start, emb[tok0], emb[tok1]] per sequence -----
__global__ __launch_bounds__(256) void build_tgt(
    const float* __restrict__ start, const float* __restrict__ emb,
    const int* __restrict__ toks, float* __restrict__ outF, bf16* __restrict__ outB)
{
    int r = blockIdx.x;               // 0..3071, r = n*3 + p
    int n = r / 3, p = r % 3;
    const float* src = (p == 0) ? start : emb + (size_t)toks[n * 3 + (p - 1)] * 768;
    int t = threadIdx.x;
    #pragma unroll
    for (int j = 0; j < 3; j++) {
        int c = t + j * 256;
        float v = src[c];
        outF[(size_t)r * 768 + c] = v;
        outB[(size_t)r * 768 + c] = (bf16)v;
    }
}

// ---------------- 3-token causal self-attention, one wave per (n,head) -------
__global__ __launch_bounds__(64) void attn3(
    const float* __restrict__ qkv, bf16* __restrict__ o)
{
    int blk = blockIdx.x;             // n*4 + h
    int n = blk >> 2, h = blk & 3;
    int lane = threadIdx.x;
    const float* base = qkv + (size_t)n * 3 * 2304 + h * 192;
    float q[3][3], k[3][3], v[3][3];
    #pragma unroll
    for (int p = 0; p < 3; p++)
        #pragma unroll
        for (int j = 0; j < 3; j++) {
            int d = lane + j * 64;
            q[p][j] = base[p * 2304 + d];
            k[p][j] = base[p * 2304 + 768 + d];
            v[p][j] = base[p * 2304 + 1536 + d];
        }
    float s[3][3];
    #pragma unroll
    for (int p = 0; p < 3; p++)
        #pragma unroll
        for (int pk = 0; pk < 3; pk++) {
            if (pk > p) continue;
            float ps = q[p][0] * k[pk][0] + q[p][1] * k[pk][1] + q[p][2] * k[pk][2];
            #pragma unroll
            for (int off = 32; off; off >>= 1) ps += __shfl_xor(ps, off);
            s[p][pk] = ps * 0.072168783648703220563f;   // 1/sqrt(192)
        }
    float a[3][3] = {};
    a[0][0] = 1.f;
    {
        float m = fmaxf(s[1][0], s[1][1]);
        float e0 = expf(s[1][0] - m), e1 = expf(s[1][1] - m);
        float inv = 1.f / (e0 + e1);
        a[1][0] = e0 * inv; a[1][1] = e1 * inv;
    }
    {
        float m = fmaxf(fmaxf(s[2][0], s[2][1]), s[2][2]);
        float e0 = expf(s[2][0] - m), e1 = expf(s[2][1] - m), e2 = expf(s[2][2] - m);
        float inv = 1.f / (e0 + e1 + e2);
        a[2][0] = e0 * inv; a[2][1] = e1 * inv; a[2][2] = e2 * inv;
    }
    bf16* ob = o + (size_t)n * 3 * 768 + h * 192;
    #pragma unroll
    for (int p = 0; p < 3; p++)
        #pragma unroll
        for (int j = 0; j < 3; j++) {
            float val = a[p][0] * v[0][j];
            if (p >= 1) val += a[p][1] * v[1][j];
            if (p >= 2) val += a[p][2] * v[2][j];
            ob[p * 768 + lane + j * 64] = (bf16)val;
        }
}

// ---------------- x = LN(a + b) ; b optionally broadcast over 3 positions ----
__global__ __launch_bounds__(256) void add_ln(
    const float* __restrict__ a, const float* __restrict__ b,
    const float* __restrict__ g, const float* __restrict__ be,
    float* __restrict__ outF, bf16* __restrict__ outB, int bcast)
{
    int r = blockIdx.x;
    int t = threadIdx.x;
    const float* ar = a + (size_t)r * 768;
    const float* br = b + (size_t)(bcast ? (r / 3) : r) * 768;
    float x[3];
    float s = 0.f, sq = 0.f;
    #pragma unroll
    for (int j = 0; j < 3; j++) {
        int c = t + j * 256;
        x[j] = ar[c] + br[c];
        s += x[j]; sq += x[j] * x[j];
    }
    #pragma unroll
    for (int off = 32; off; off >>= 1) {
        s += __shfl_xor(s, off);
        sq += __shfl_xor(sq, off);
    }
    __shared__ float ls[4], lq[4];
    int wv = t >> 6;
    if ((t & 63) == 0) { ls[wv] = s; lq[wv] = sq; }
    __syncthreads();
    s = ls[0] + ls[1] + ls[2] + ls[3];
    sq = lq[0] + lq[1] + lq[2] + lq[3];
    float mean = s * (1.f / 768.f);
    float var = sq * (1.f / 768.f) - mean * mean;
    float inv = rsqrtf(var + 1e-5f);
    #pragma unroll
    for (int j = 0; j < 3; j++) {
        int c = t + j * 256;
        float y = (x[j] - mean) * inv * g[c] + be[c];
        if (outF) outF[(size_t)r * 768 + c] = y;
        if (outB) outB[(size_t)r * 768 + c] = (bf16)y;
    }
}

// =============================================================================
static inline void run_gemm(const bf16* A, const bf16* W, const float* bias,
                            float* outF, bf16* outB, int M, int Npad, int K,
                            int ldo, int Nstore, int relu, hipStream_t s)
{
    dim3 grid(Npad / BN, M / BM);
    gemm_bt<<<grid, 256, 0, s>>>(A, W, bias, outF, outB, M, K, ldo, Nstore, relu);
}

static inline void run_cvt(const float* in, bf16* out, size_t nvalid,
                           size_t ntotal, hipStream_t s)
{
    int blocks = (int)((ntotal / 4 + 255) / 256);
    cvt_bf16<<<blocks, 256, 0, s>>>(in, out, nvalid, ntotal);
}

extern "C" void kernel_launch(void* const* d_in, const int* in_sizes, int n_in,
                              void* d_out, int out_size, void* d_ws, size_t ws_size,
                              hipStream_t stream)
{
    const float* enc      = (const float*)d_in[0];   // (1024, 768)
    const int*   toks     = (const int*)d_in[1];     // (1024, 3)
    const float* start    = (const float*)d_in[2];   // (1, 768)
    const float* emb      = (const float*)d_in[3];   // (51865, 768)
    const float* sa_in_w  = (const float*)d_in[4];   // (2304, 768)
    const float* sa_in_b  = (const float*)d_in[5];
    const float* sa_out_w = (const float*)d_in[6];   // (768, 768)
    const float* sa_out_b = (const float*)d_in[7];
    const float* ca_in_w  = (const float*)d_in[8];   // (2304, 768); only Wv used
    const float* ca_in_b  = (const float*)d_in[9];
    const float* ca_out_w = (const float*)d_in[10];  // (768, 768)
    const float* ca_out_b = (const float*)d_in[11];
    const float* lin1_w   = (const float*)d_in[12];  // (2048, 768)
    const float* lin1_b   = (const float*)d_in[13];
    const float* lin2_w   = (const float*)d_in[14];  // (768, 2048)
    const float* lin2_b   = (const float*)d_in[15];
    const float* ln1_g    = (const float*)d_in[16];
    const float* ln1_bb   = (const float*)d_in[17];
    const float* ln2_g    = (const float*)d_in[18];
    const float* ln2_bb   = (const float*)d_in[19];
    const float* ln3_g    = (const float*)d_in[20];
    const float* ln3_bb   = (const float*)d_in[21];
    const float* proj_w   = (const float*)d_in[22];  // (51865, 768)
    float* out = (float*)d_out;

    const int NTOK = 3072;          // B*T*NT
    const int NM   = 1024;          // B*T
    const int H    = 768;
    const int V    = 51865;
    const int VPAD = 51968;         // 203*256
    const int DFF  = 2048;

    char* p = (char*)d_ws;
    auto alloc = [&](size_t bytes) {
        void* r = (void*)p;
        p += (bytes + 255) & ~(size_t)255;
        return r;
    };
    float* tgt_f = (float*)alloc((size_t)NTOK * H * 4);
    float* x1_f  = (float*)alloc((size_t)NTOK * H * 4);
    float* x2_f  = (float*)alloc((size_t)NTOK * H * 4);
    float* big_f = (float*)alloc((size_t)NTOK * 2304 * 4);  // qkv / gemm fp32 outs
    bf16*  actA  = (bf16*)alloc((size_t)NTOK * 2304 * 2);   // bf16 activations A
    bf16*  actB  = (bf16*)alloc((size_t)NTOK * DFF * 2);    // bf16 activations B
    bf16*  Wbf   = (bf16*)alloc((size_t)VPAD * H * 2);      // bf16 weights (reused)
    bf16*  mem_bf = actB;                                   // (1024,768) carved
    bf16*  v_bf   = actB + (size_t)NM * H;                  // (1024,768) carved
    float* cao_f  = big_f + (size_t)NTOK * H;               // (1024,768) carved

    // 1. tgt = [start, emb[t0], emb[t1]]
    build_tgt<<<NTOK, 256, 0, stream>>>(start, emb, toks, tgt_f, actA);

    // 2. qkv = tgt @ sa_in_w.T + b       (3072 x 2304)
    run_cvt(sa_in_w, Wbf, (size_t)2304 * H, (size_t)2304 * H, stream);
    run_gemm(actA, Wbf, sa_in_b, big_f, nullptr, NTOK, 2304, H, 2304, 2304, 0, stream);

    // 3. 3x3 causal attention -> o (bf16)
    attn3<<<NM * 4, 64, 0, stream>>>(big_f, actA);

    // 4. sa = o @ sa_out_w.T + b
    run_cvt(sa_out_w, Wbf, (size_t)H * H, (size_t)H * H, stream);
    run_gemm(actA, Wbf, sa_out_b, big_f, nullptr, NTOK, H, H, H, H, 0, stream);

    // 5. x1 = LN1(tgt + sa)
    add_ln<<<NTOK, 256, 0, stream>>>(tgt_f, big_f, ln1_g, ln1_bb, x1_f, nullptr, 0);

    // 6. cross-attn (Lk=1 => softmax==1 => output == V projection of memory)
    run_cvt(enc, mem_bf, (size_t)NM * H, (size_t)NM * H, stream);
    run_cvt(ca_in_w + (size_t)1536 * H, Wbf, (size_t)H * H, (size_t)H * H, stream);
    run_gemm(mem_bf, Wbf, ca_in_b + 1536, nullptr, v_bf, NM, H, H, H, H, 0, stream);
    run_cvt(ca_out_w, Wbf, (size_t)H * H, (size_t)H * H, stream);
    run_gemm(v_bf, Wbf, ca_out_b, cao_f, nullptr, NM, H, H, H, H, 0, stream);

    // 7. x2 = LN2(x1 + ca_out[broadcast])
    add_ln<<<NTOK, 256, 0, stream>>>(x1_f, cao_f, ln2_g, ln2_bb, x2_f, actA, 1);

    // 8. ff1 = relu(x2 @ lin1_w.T + b)   (bf16 only)
    run_cvt(lin1_w, Wbf, (size_t)DFF * H, (size_t)DFF * H, stream);
    run_gemm(actA, Wbf, lin1_b, nullptr, actB, NTOK, DFF, H, DFF, DFF, 1, stream);

    // 9. ff2 = ff1 @ lin2_w.T + b        (K = 2048)
    run_cvt(lin2_w, Wbf, (size_t)H * DFF, (size_t)H * DFF, stream);
    run_gemm(actB, Wbf, lin2_b, big_f, nullptr, NTOK, H, DFF, H, H, 0, stream);

    // 10. x3 = LN3(x2 + ff2) -> bf16 only
    add_ln<<<NTOK, 256, 0, stream>>>(x2_f, big_f, ln3_g, ln3_bb, nullptr, actA, 0);

    // 11. logits = x3 @ proj_w.T  (3072 x 51865) -- deep-slack 2-barrier kernel
    run_cvt(proj_w, Wbf, (size_t)V * H, (size_t)VPAD * H, stream);
    {
        dim3 grid((NTOK / 256) * (VPAD / 256));   // 12 * 203 = 2436
        gemm8p<<<grid, 512, 0, stream>>>(actA, Wbf, out, H, V, V, NTOK / 256);
    }
}